// Round 1
// baseline (3141.001 us; speedup 1.0000x reference)
//
#include <hip/hip_runtime.h>

// LSTM last-hidden + projection. B=256, T=4096, F=32, H=128, 4H=512.
// 64 WGs x 512 threads (8 waves, 2/SIMD); WG g owns batches [4g,4g+4) at MFMA
// A-rows {0,4,8,12}. z(4x512) = [x_t|h](4x160) @ [W;U](160x512), mfma 16x16x32 f16.
// Model (fit R1-R5): MFMA issue ~19.4cy/SIMD, dependent-use latency L~240cy,
// VALU-reads of MFMA dests ~26.5cy each. t_step ~1692cy = 776 issue floor + tail.
// R6 (this round): attack the tail.
//  (a) chain issue order {g,i,f,o}: z2 (tanh gate, longest act chain) completes
//      ~230cy earlier; per-gate act starts as each z lands; o-gate lands last
//      (needed latest, at hn = go*th).
//  (b) log2e folded into W/U/b columns (-L2E for i,f,o; +2*L2E for g); c-state
//      kept pre-scaled by 2*L2E -> all transcendentals are bare v_exp_f32.
//  (c) lgkm-only barrier (inline asm) -> no vmcnt(0) drain of the x(t+2)
//      prefetch at each step boundary.
//  (d) ds_reads issued in first-link use order a3,a1,a2,a4; x-prefetch address
//      calc moved after first-link MFMA issue.

#define TT 4096
#define FF 32
#define HH 128
#define NG 512

typedef float f32x4 __attribute__((ext_vector_type(4)));
typedef _Float16 h16x8 __attribute__((ext_vector_type(8)));

#if __has_builtin(__builtin_amdgcn_exp2f)
#define EX2(v) __builtin_amdgcn_exp2f(v)
#else
#define EX2(v) exp2f(v)
#endif
#define RCP(v) __builtin_amdgcn_rcpf(v)

__global__ __launch_bounds__(512, 2)
void lstm_seq_kernel(const float* __restrict__ x,        // (B,T,F)
                     const int*   __restrict__ seq_lens, // (B)
                     const float* __restrict__ W,        // (F,4H)
                     const float* __restrict__ U,        // (H,4H)
                     const float* __restrict__ bias,     // (4H)
                     const float* __restrict__ Wf,       // (H)
                     const float* __restrict__ bfp,      // (1)
                     float* __restrict__ out)            // (B)
{
    // h-only A staging: A[par][kc-1][slot][j] == A[m=slot&15][k=kc*32+(slot>>4)*8+j]
    __shared__ _Float16 A[2][4][64][8];
    __shared__ float outAcc[4];

    const int tid  = threadIdx.x;
    const int lane = tid & 63;
    const int w    = tid >> 6;     // wave 0..7
    const int c    = lane & 15;    // n-col within tile
    const int q    = lane >> 4;    // quad 0..3 -> this lane's batch
    const int b0   = blockIdx.x * 4;
    const int hc   = w * 16 + c;   // this lane's LSTM cell (0..127)

    {
        _Float16* p = &A[0][0][0][0];
        for (int i = tid; i < 2 * 4 * 64 * 8; i += 512) p[i] = (_Float16)0.f;
        if (tid < 4) outAcc[tid] = 0.f;
    }

    const int sl0 = seq_lens[b0 + 0], sl1 = seq_lens[b0 + 1];
    const int sl2 = seq_lens[b0 + 2], sl3 = seq_lens[b0 + 3];
    const int gmax = max(max(sl0, sl1), max(sl2, sl3));
    const int slq  = seq_lens[b0 + q];

    const float L2E = 1.44269504f;      // log2(e)
    const float K2  = 2.88539008f;      // 2*log2(e)

    // register-resident weights: wave w -> tiles {8j+w}, j = gate i,f,g,o; n = j*128+hc
    // B-frag: lane holds B[k = kc*32 + q*8 + e][n]
    // Columns pre-scaled: i,f,o by -L2E (sigmoid via exp2), g by +2*L2E (tanh via exp2).
    h16x8 bh[4][5];
    #pragma unroll
    for (int j = 0; j < 4; ++j) {
        const int n = j * 128 + hc;
        const float gsc = (j == 2) ? K2 : -L2E;
        #pragma unroll
        for (int kc = 0; kc < 5; ++kc) {
            #pragma unroll
            for (int e = 0; e < 8; ++e) {
                const int k = kc * 32 + q * 8 + e;
                float v = (k < FF) ? W[k * NG + n] : U[(k - FF) * NG + n];
                bh[j][kc][e] = (_Float16)(v * gsc);
            }
        }
    }

    // bias folded into accX's C operand (only element [0] is ever read), pre-scaled
    f32x4 biasC[4];
    #pragma unroll
    for (int j = 0; j < 4; ++j) {
        const float gsc = (j == 2) ? K2 : -L2E;
        const float bv = bias[j * HH + hc] * gsc;
        f32x4 t = {bv, bv, bv, bv};
        biasC[j] = t;
    }
    const float wfv = Wf[hc];
    const int kk    = FF + hc;                        // K-position of this h element
    const int wkc   = (kk >> 5) - 1;                  // 0..3
    const int wslot = ((kk >> 3) & 3) * 16 + 4 * q;   // batch q at row 4q
    const int wj    = kk & 7;

    // x A-fragment: lane needs A[m=c][k=q*8+e]; real rows m=4b -> lanes c%4==0, batch=c>>2
    const bool xact = ((c & 3) == 0);
    const float* xrow = x + (size_t)(b0 + (c >> 2)) * TT * FF + q * 8;

    const f32x4 zero4 = {0.f, 0.f, 0.f, 0.f};

    // pre-loop: accX for t=0 (x_0·W + bias, scaled), prefetch x_1 into registers
    f32x4 accX[4];
    {
        float4 xa = {0,0,0,0}, xb = {0,0,0,0};
        if (xact) {
            xa = *(const float4*)(xrow);
            xb = *(const float4*)(xrow + 4);
        }
        h16x8 xf = { (_Float16)xa.x, (_Float16)xa.y, (_Float16)xa.z, (_Float16)xa.w,
                     (_Float16)xb.x, (_Float16)xb.y, (_Float16)xb.z, (_Float16)xb.w };
        #pragma unroll
        for (int j = 0; j < 4; ++j)
            accX[j] = __builtin_amdgcn_mfma_f32_16x16x32_f16(xf, bh[j][0], biasC[j], 0, 0, 0);
    }
    float4 cxa = {0,0,0,0}, cxb = {0,0,0,0};    // x_{t+1} (registers)
    if (xact) {
        const float* p = xrow + (size_t)((1 < TT) ? 1 : TT - 1) * FF;
        cxa = *(const float4*)(p);
        cxb = *(const float4*)(p + 4);
    }
    __syncthreads();

    float cs = 0.f, hh = 0.f;   // cs = 2*log2e * c  (pre-scaled cell state)

    for (int t = 0; t < gmax; ++t) {
        const int par = t & 1, pnx = par ^ 1;

        // post-barrier: h A-fragments, issued in first-link use order
        h16x8 a3 = *(const h16x8*)&A[par][2][lane][0];
        h16x8 a1 = *(const h16x8*)&A[par][0][lane][0];
        h16x8 a2 = *(const h16x8*)&A[par][1][lane][0];
        h16x8 a4 = *(const h16x8*)&A[par][3][lane][0];

        // first links, gate order {g,i,f,o}; pc seeded with accX (x-part+bias)
        f32x4 qc2 = __builtin_amdgcn_mfma_f32_16x16x32_f16(a3, bh[2][3], zero4,   0, 0, 0);
        f32x4 pc2 = __builtin_amdgcn_mfma_f32_16x16x32_f16(a1, bh[2][1], accX[2], 0, 0, 0);
        f32x4 qc0 = __builtin_amdgcn_mfma_f32_16x16x32_f16(a3, bh[0][3], zero4,   0, 0, 0);
        f32x4 pc0 = __builtin_amdgcn_mfma_f32_16x16x32_f16(a1, bh[0][1], accX[0], 0, 0, 0);
        f32x4 qc1 = __builtin_amdgcn_mfma_f32_16x16x32_f16(a3, bh[1][3], zero4,   0, 0, 0);
        f32x4 pc1 = __builtin_amdgcn_mfma_f32_16x16x32_f16(a1, bh[1][1], accX[1], 0, 0, 0);
        f32x4 qc3 = __builtin_amdgcn_mfma_f32_16x16x32_f16(a3, bh[3][3], zero4,   0, 0, 0);
        f32x4 pc3 = __builtin_amdgcn_mfma_f32_16x16x32_f16(a1, bh[3][1], accX[3], 0, 0, 0);

        // issue x_{t+2} load (2-step latency cover); after first-link issue so
        // its address VALU ops don't delay the MFMA front
        float4 nxa = {0,0,0,0}, nxb = {0,0,0,0};
        if (xact) {
            const int tl = (t + 2 < TT) ? (t + 2) : (TT - 1);
            const float* p = xrow + (size_t)tl * FF;
            nxa = *(const float4*)(p);
            nxb = *(const float4*)(p + 4);
        }

        // second links, same gate order
        pc2 = __builtin_amdgcn_mfma_f32_16x16x32_f16(a2, bh[2][2], pc2, 0, 0, 0);
        qc2 = __builtin_amdgcn_mfma_f32_16x16x32_f16(a4, bh[2][4], qc2, 0, 0, 0);
        pc0 = __builtin_amdgcn_mfma_f32_16x16x32_f16(a2, bh[0][2], pc0, 0, 0, 0);
        qc0 = __builtin_amdgcn_mfma_f32_16x16x32_f16(a4, bh[0][4], qc0, 0, 0, 0);
        pc1 = __builtin_amdgcn_mfma_f32_16x16x32_f16(a2, bh[1][2], pc1, 0, 0, 0);
        qc1 = __builtin_amdgcn_mfma_f32_16x16x32_f16(a4, bh[1][4], qc1, 0, 0, 0);
        pc3 = __builtin_amdgcn_mfma_f32_16x16x32_f16(a2, bh[3][2], pc3, 0, 0, 0);
        qc3 = __builtin_amdgcn_mfma_f32_16x16x32_f16(a4, bh[3][4], qc3, 0, 0, 0);

        // per-gate join + act, started in completion order (g first, o last).
        // z pre-scaled: i,f,o by -L2E -> sigmoid = rcp(1+exp2(z));
        // g by +2*L2E -> tanh = 1 - 2*rcp(exp2(z)+1).
        float z2 = pc2[0] + qc2[0];
        float gg = fmaf(-2.f, RCP(EX2(z2) + 1.f), 1.f);
        float z0 = pc0[0] + qc0[0];
        float gi = RCP(1.f + EX2(z0));
        float z1 = pc1[0] + qc1[0];
        float gf = RCP(1.f + EX2(z1));
        float z3 = pc3[0] + qc3[0];
        float go = RCP(1.f + EX2(z3));
        float csn = fmaf(gf, cs, (gi * gg) * K2);            // scaled c_new
        float th  = fmaf(-2.f, RCP(EX2(csn) + 1.f), 1.f);    // tanh(c_new)
        float hn  = go * th;
        const bool upd = (t < slq);
        cs = upd ? csn : cs;
        hh = upd ? hn : hh;
        A[pnx][wkc][wslot][wj] = (_Float16)hh;

        // accX for t+1 (x_{t+1}·W + bias, scaled), pre-barrier
        {
            h16x8 xf = { (_Float16)cxa.x, (_Float16)cxa.y, (_Float16)cxa.z, (_Float16)cxa.w,
                         (_Float16)cxb.x, (_Float16)cxb.y, (_Float16)cxb.z, (_Float16)cxb.w };
            #pragma unroll
            for (int j = 0; j < 4; ++j)
                accX[j] = __builtin_amdgcn_mfma_f32_16x16x32_f16(xf, bh[j][0], biasC[j], 0, 0, 0);
        }
        cxa = nxa; cxb = nxb;

        // lgkm-only barrier: h is in LDS (lgkm); do NOT drain vmcnt (x prefetch
        // stays in flight across the step boundary).
        asm volatile("s_waitcnt lgkmcnt(0)\n\ts_barrier" ::: "memory");
    }

    // epilogue: out[b] = h @ Wf + bf
    float p = hh * wfv;
    p += __shfl_down(p, 8, 16);
    p += __shfl_down(p, 4, 16);
    p += __shfl_down(p, 2, 16);
    p += __shfl_down(p, 1, 16);
    if (c == 0) atomicAdd(&outAcc[q], p);
    __syncthreads();
    if (tid < 4) out[b0 + tid] = outAcc[tid] + bfp[0];
}

extern "C" void kernel_launch(void* const* d_in, const int* in_sizes, int n_in,
                              void* d_out, int out_size, void* d_ws, size_t ws_size,
                              hipStream_t stream) {
    const float* x        = (const float*)d_in[0];
    const int*   seq_lens = (const int*)d_in[1];
    const float* W        = (const float*)d_in[2];
    const float* U        = (const float*)d_in[3];
    const float* bias     = (const float*)d_in[4];
    const float* Wf       = (const float*)d_in[5];
    const float* bfp      = (const float*)d_in[6];
    float* out = (float*)d_out;

    lstm_seq_kernel<<<dim3(64), dim3(512), 0, stream>>>(x, seq_lens, W, U, bias, Wf, bfp, out);
}

// Round 3
// 2894.044 us; speedup vs baseline: 1.0853x; 1.0853x over previous
//
#include <hip/hip_runtime.h>

// LSTM last-hidden + projection. B=256, T=4096, F=32, H=128, 4H=512.
// 64 WGs x 512 threads (8 waves, 2/SIMD); WG g owns batches [4g,4g+4) at MFMA
// A-rows {0,4,8,12}. z(4x512) = [x_t|h](4x160) @ [W;U](160x512), mfma 16x16x32 f16.
// Model (fit R1-R5): MFMA issue ~19.4cy/SIMD, dependent-use latency L~240cy,
// VALU-reads of MFMA dests are expensive (R4: 20 reads => +530cy/step).
// R5 (proven 2890us): per gate TWO depth-2 chains joined with ONE add; chainP
// seeded C=accX (x-part+bias, pre-barrier from register x_t), chainQ seeded C=0;
// x double-prefetched (t+2).
// R6 (bundle: chain reorder + lgkm-only barrier + folding) REGRESSED to 3010us
// -> reverted everything except the scheduling-neutral piece:
// R7: log2e folded into W/U/b columns (-L2E for i,f,o; +2*L2E for g); cell
// state kept pre-scaled by 2*log2e; g-gate fma constants produce K2*tanh
// directly. All transcendentals are bare v_exp_f32, no leading multiplies.
// Structure (ds_read order, chain order, __syncthreads) is R5-identical.
// (R7 bench attempt failed on container acquisition; resubmitted unchanged.)

#define TT 4096
#define FF 32
#define HH 128
#define NG 512

typedef float f32x4 __attribute__((ext_vector_type(4)));
typedef _Float16 h16x8 __attribute__((ext_vector_type(8)));

#if __has_builtin(__builtin_amdgcn_exp2f)
#define EX2(v) __builtin_amdgcn_exp2f(v)
#else
#define EX2(v) exp2f(v)
#endif
#define RCP(v) __builtin_amdgcn_rcpf(v)

__global__ __launch_bounds__(512, 2)
void lstm_seq_kernel(const float* __restrict__ x,        // (B,T,F)
                     const int*   __restrict__ seq_lens, // (B)
                     const float* __restrict__ W,        // (F,4H)
                     const float* __restrict__ U,        // (H,4H)
                     const float* __restrict__ bias,     // (4H)
                     const float* __restrict__ Wf,       // (H)
                     const float* __restrict__ bfp,      // (1)
                     float* __restrict__ out)            // (B)
{
    // h-only A staging: A[par][kc-1][slot][j] == A[m=slot&15][k=kc*32+(slot>>4)*8+j]
    __shared__ _Float16 A[2][4][64][8];
    __shared__ float outAcc[4];

    const int tid  = threadIdx.x;
    const int lane = tid & 63;
    const int w    = tid >> 6;     // wave 0..7
    const int c    = lane & 15;    // n-col within tile
    const int q    = lane >> 4;    // quad 0..3 -> this lane's batch
    const int b0   = blockIdx.x * 4;
    const int hc   = w * 16 + c;   // this lane's LSTM cell (0..127)

    {
        _Float16* p = &A[0][0][0][0];
        for (int i = tid; i < 2 * 4 * 64 * 8; i += 512) p[i] = (_Float16)0.f;
        if (tid < 4) outAcc[tid] = 0.f;
    }

    const int sl0 = seq_lens[b0 + 0], sl1 = seq_lens[b0 + 1];
    const int sl2 = seq_lens[b0 + 2], sl3 = seq_lens[b0 + 3];
    const int gmax = max(max(sl0, sl1), max(sl2, sl3));
    const int slq  = seq_lens[b0 + q];

    const float L2E = 1.44269504f;      // log2(e)
    const float K2  = 2.88539008f;      // 2*log2(e)

    // register-resident weights: wave w -> tiles {8j+w}, j = gate i,f,g,o; n = j*128+hc
    // B-frag: lane holds B[k = kc*32 + q*8 + e][n]
    // Columns pre-scaled: i,f,o by -L2E (sigmoid via bare exp2), g by +2*L2E
    // (tanh via bare exp2).
    h16x8 bh[4][5];
    #pragma unroll
    for (int j = 0; j < 4; ++j) {
        const int n = j * 128 + hc;
        const float gsc = (j == 2) ? K2 : -L2E;
        #pragma unroll
        for (int kc = 0; kc < 5; ++kc) {
            #pragma unroll
            for (int e = 0; e < 8; ++e) {
                const int k = kc * 32 + q * 8 + e;
                float v = (k < FF) ? W[k * NG + n] : U[(k - FF) * NG + n];
                bh[j][kc][e] = (_Float16)(v * gsc);
            }
        }
    }

    // bias folded into accX's C operand (only element [0] is ever read), pre-scaled
    f32x4 biasC[4];
    #pragma unroll
    for (int j = 0; j < 4; ++j) {
        const float gsc = (j == 2) ? K2 : -L2E;
        const float bv = bias[j * HH + hc] * gsc;
        f32x4 t = {bv, bv, bv, bv};
        biasC[j] = t;
    }
    const float wfv = Wf[hc];
    const int kk    = FF + hc;                        // K-position of this h element
    const int wkc   = (kk >> 5) - 1;                  // 0..3
    const int wslot = ((kk >> 3) & 3) * 16 + 4 * q;   // batch q at row 4q
    const int wj    = kk & 7;

    // x A-fragment: lane needs A[m=c][k=q*8+e]; real rows m=4b -> lanes c%4==0, batch=c>>2
    const bool xact = ((c & 3) == 0);
    const float* xrow = x + (size_t)(b0 + (c >> 2)) * TT * FF + q * 8;

    const f32x4 zero4 = {0.f, 0.f, 0.f, 0.f};

    // pre-loop: accX for t=0 (x_0·W + bias, scaled), prefetch x_1 into registers
    f32x4 accX[4];
    {
        float4 xa = {0,0,0,0}, xb = {0,0,0,0};
        if (xact) {
            xa = *(const float4*)(xrow);
            xb = *(const float4*)(xrow + 4);
        }
        h16x8 xf = { (_Float16)xa.x, (_Float16)xa.y, (_Float16)xa.z, (_Float16)xa.w,
                     (_Float16)xb.x, (_Float16)xb.y, (_Float16)xb.z, (_Float16)xb.w };
        #pragma unroll
        for (int j = 0; j < 4; ++j)
            accX[j] = __builtin_amdgcn_mfma_f32_16x16x32_f16(xf, bh[j][0], biasC[j], 0, 0, 0);
    }
    float4 cxa = {0,0,0,0}, cxb = {0,0,0,0};    // x_{t+1} (registers)
    if (xact) {
        const float* p = xrow + (size_t)((1 < TT) ? 1 : TT - 1) * FF;
        cxa = *(const float4*)(p);
        cxb = *(const float4*)(p + 4);
    }
    __syncthreads();

    float cs = 0.f, hh = 0.f;   // cs = 2*log2e * c  (pre-scaled cell state)

    for (int t = 0; t < gmax; ++t) {
        const int par = t & 1, pnx = par ^ 1;

        // post-barrier: h A-fragments (4 x ds_read_b128)
        h16x8 a1 = *(const h16x8*)&A[par][0][lane][0];
        h16x8 a2 = *(const h16x8*)&A[par][1][lane][0];
        h16x8 a3 = *(const h16x8*)&A[par][2][lane][0];
        h16x8 a4 = *(const h16x8*)&A[par][3][lane][0];

        // issue x_{t+2} load early (2-step latency cover)
        float4 nxa = {0,0,0,0}, nxb = {0,0,0,0};
        if (xact) {
            const int tl = (t + 2 < TT) ? (t + 2) : (TT - 1);
            const float* p = xrow + (size_t)tl * FF;
            nxa = *(const float4*)(p);
            nxb = *(const float4*)(p + 4);
        }

        // two depth-2 chains per gate; all 8 first-links independent
        f32x4 pc[4], qc[4];
        #pragma unroll
        for (int j = 0; j < 4; ++j)
            qc[j] = __builtin_amdgcn_mfma_f32_16x16x32_f16(a3, bh[j][3], zero4, 0, 0, 0);
        #pragma unroll
        for (int j = 0; j < 4; ++j)
            pc[j] = __builtin_amdgcn_mfma_f32_16x16x32_f16(a1, bh[j][1], accX[j], 0, 0, 0);
        #pragma unroll
        for (int j = 0; j < 4; ++j)
            qc[j] = __builtin_amdgcn_mfma_f32_16x16x32_f16(a4, bh[j][4], qc[j], 0, 0, 0);
        #pragma unroll
        for (int j = 0; j < 4; ++j)
            pc[j] = __builtin_amdgcn_mfma_f32_16x16x32_f16(a2, bh[j][2], pc[j], 0, 0, 0);

        // join (8 VALU reads of MFMA dests) + activation; row 4q+0 = batch q
        // z pre-scaled: i,f,o by -L2E -> sigmoid = rcp(1+exp2(z));
        // g by +2*L2E -> gg' = K2*tanh = fmaf(-2K2, rcp(exp2(z)+1), K2).
        float z0 = pc[0][0] + qc[0][0];
        float z1 = pc[1][0] + qc[1][0];
        float z2 = pc[2][0] + qc[2][0];
        float z3 = pc[3][0] + qc[3][0];

        float gi = RCP(1.f + EX2(z0));
        float gf = RCP(1.f + EX2(z1));
        float gg = fmaf(-2.f * K2, RCP(EX2(z2) + 1.f), K2);   // = K2*tanh(z2/K2-scale)
        float go = RCP(1.f + EX2(z3));
        float csn = fmaf(gf, cs, gi * gg);                    // scaled c_new (=K2*c_new)
        float th  = fmaf(-2.f, RCP(EX2(csn) + 1.f), 1.f);     // tanh(c_new)
        float hn  = go * th;
        const bool upd = (t < slq);
        cs = upd ? csn : cs;
        hh = upd ? hn : hh;
        A[pnx][wkc][wslot][wj] = (_Float16)hh;

        // accX for t+1 (x_{t+1}·W + bias, scaled), pre-barrier: ready when chains restart
        {
            h16x8 xf = { (_Float16)cxa.x, (_Float16)cxa.y, (_Float16)cxa.z, (_Float16)cxa.w,
                         (_Float16)cxb.x, (_Float16)cxb.y, (_Float16)cxb.z, (_Float16)cxb.w };
            #pragma unroll
            for (int j = 0; j < 4; ++j)
                accX[j] = __builtin_amdgcn_mfma_f32_16x16x32_f16(xf, bh[j][0], biasC[j], 0, 0, 0);
        }
        cxa = nxa; cxb = nxb;

        __syncthreads();
    }

    // epilogue: out[b] = h @ Wf + bf
    float p = hh * wfv;
    p += __shfl_down(p, 8, 16);
    p += __shfl_down(p, 4, 16);
    p += __shfl_down(p, 2, 16);
    p += __shfl_down(p, 1, 16);
    if (c == 0) atomicAdd(&outAcc[q], p);
    __syncthreads();
    if (tid < 4) out[b0 + tid] = outAcc[tid] + bfp[0];
}

extern "C" void kernel_launch(void* const* d_in, const int* in_sizes, int n_in,
                              void* d_out, int out_size, void* d_ws, size_t ws_size,
                              hipStream_t stream) {
    const float* x        = (const float*)d_in[0];
    const int*   seq_lens = (const int*)d_in[1];
    const float* W        = (const float*)d_in[2];
    const float* U        = (const float*)d_in[3];
    const float* bias     = (const float*)d_in[4];
    const float* Wf       = (const float*)d_in[5];
    const float* bfp      = (const float*)d_in[6];
    float* out = (float*)d_out;

    lstm_seq_kernel<<<dim3(64), dim3(512), 0, stream>>>(x, seq_lens, W, U, bias, Wf, bfp, out);
}